// Round 1
// baseline (887.674 us; speedup 1.0000x reference)
//
#include <hip/hip_runtime.h>
#include <hip/hip_bf16.h>
#include <math.h>

// ---------------------------------------------------------------------------
// GATv2 2-layer + linear head, MI355X (gfx950)
// Pipeline:
//   CSR build (hist -> scan -> scatter)   [by dst]
//   gemm_f32: xl1 = x@Wl1+bl1 ; xr1 = x@Wr1+br1
//   gat_node (mode 0): online-softmax attention -> h1 = relu(agg + bias1) [N,256]
//   gemm_f32: xl2 = h1@Wl2+bl2 ; xr2 = h1@Wr2+br2
//   gat_node (mode 1): -> h2 = relu(mean_heads(agg) + bias2) [N,64]
//   final_linear: out = h2@Wc + bc [N,40]
// ---------------------------------------------------------------------------

#define IN_DIM 256
#define HIDHC 256   // HEADS*HID
#define HID 64
#define HEADS 4
#define OUT_DIM 40

// -------------------- CSR build --------------------

__global__ void edge_hist(const int* __restrict__ dst, int* __restrict__ deg, int E) {
    int i = blockIdx.x * blockDim.x + threadIdx.x;
    if (i < E) atomicAdd(&deg[dst[i]], 1);
}

__global__ void scan_offsets(const int* __restrict__ deg, int* __restrict__ offsets,
                             int* __restrict__ cursor, int n) {
    __shared__ int wsum[16];
    __shared__ int wpref[17];
    int tid  = threadIdx.x;
    int lane = tid & 63, wid = tid >> 6;
    int carry = 0;
    if (tid == 0) offsets[0] = 0;
    for (int base = 0; base < n; base += 1024) {
        int i = base + tid;
        int v = (i < n) ? deg[i] : 0;
        int inc = v;
        #pragma unroll
        for (int off = 1; off < 64; off <<= 1) {
            int t = __shfl_up(inc, off, 64);
            if (lane >= off) inc += t;
        }
        if (lane == 63) wsum[wid] = inc;
        __syncthreads();
        if (tid == 0) {
            int s = 0;
            #pragma unroll
            for (int w = 0; w < 16; ++w) { wpref[w] = s; s += wsum[w]; }
            wpref[16] = s;
        }
        __syncthreads();
        int incl = inc + wpref[wid] + carry;
        if (i < n) { offsets[i + 1] = incl; cursor[i] = incl - v; }
        carry += wpref[16];
        __syncthreads();
    }
}

__global__ void edge_scatter(const int* __restrict__ src, const int* __restrict__ dst,
                             int* __restrict__ cursor, int* __restrict__ csr_src, int E) {
    int i = blockIdx.x * blockDim.x + threadIdx.x;
    if (i < E) {
        int p = atomicAdd(&cursor[dst[i]], 1);
        csr_src[p] = src[i];
    }
}

// -------------------- fp32 GEMM: C[M,256] = A[M,256] @ W[256,256] + bias --------------------
// 128x128 tile, BK=8, 256 threads, 8x8 microtile.

__global__ __launch_bounds__(256) void gemm_f32(
    const float* __restrict__ A, const float* __restrict__ W,
    const float* __restrict__ bias, float* __restrict__ C, int M)
{
    const int K = 256, N = 256;
    __shared__ float As[8][128];
    __shared__ float Bs[8][128];

    int tid = threadIdx.x;
    int bm = blockIdx.x * 128;
    int bn = blockIdx.y * 128;

    int arow = tid >> 1;            // 0..127
    int acol = (tid & 1) << 2;      // 0 or 4
    int brow = tid >> 5;            // 0..7
    int bcol = (tid & 31) << 2;     // 0..124

    int tx = tid & 15;
    int ty = tid >> 4;

    float acc[8][8];
    #pragma unroll
    for (int i = 0; i < 8; ++i)
        #pragma unroll
        for (int j = 0; j < 8; ++j) acc[i][j] = 0.f;

    int aR = bm + arow;
    if (aR >= M) aR = M - 1;
    const float* Ap = A + (size_t)aR * K + acol;

    for (int k0 = 0; k0 < K; k0 += 8) {
        float4 av = *(const float4*)(Ap + k0);
        float4 bv = *(const float4*)(W + (size_t)(k0 + brow) * N + bn + bcol);
        As[acol + 0][arow] = av.x;
        As[acol + 1][arow] = av.y;
        As[acol + 2][arow] = av.z;
        As[acol + 3][arow] = av.w;
        *(float4*)&Bs[brow][bcol] = bv;
        __syncthreads();
        #pragma unroll
        for (int kk = 0; kk < 8; ++kk) {
            float4 a0 = *(const float4*)&As[kk][ty * 8];
            float4 a1 = *(const float4*)&As[kk][ty * 8 + 4];
            float4 b0 = *(const float4*)&Bs[kk][tx * 8];
            float4 b1 = *(const float4*)&Bs[kk][tx * 8 + 4];
            float a[8] = {a0.x, a0.y, a0.z, a0.w, a1.x, a1.y, a1.z, a1.w};
            float b[8] = {b0.x, b0.y, b0.z, b0.w, b1.x, b1.y, b1.z, b1.w};
            #pragma unroll
            for (int i = 0; i < 8; ++i)
                #pragma unroll
                for (int j = 0; j < 8; ++j)
                    acc[i][j] = fmaf(a[i], b[j], acc[i][j]);
        }
        __syncthreads();
    }

    #pragma unroll
    for (int i = 0; i < 8; ++i) {
        int row = bm + ty * 8 + i;
        if (row < M) {
            #pragma unroll
            for (int j = 0; j < 8; j += 4) {
                int col = bn + tx * 8 + j;
                float4 o;
                o.x = acc[i][j + 0] + bias[col + 0];
                o.y = acc[i][j + 1] + bias[col + 1];
                o.z = acc[i][j + 2] + bias[col + 2];
                o.w = acc[i][j + 3] + bias[col + 3];
                *(float4*)(C + (size_t)row * N + col) = o;
            }
        }
    }
}

// -------------------- GAT node kernel: one wave per node, online softmax --------------------
// Lane layout: quarter q (lane>>4) owns head q; lane%16 = l owns channels 4l..4l+3.
// Wave covers the full 256-float row contiguously -> coalesced dwordx4 gathers.

__device__ __forceinline__ float lrelu(float x) { return x > 0.f ? x : 0.2f * x; }

__global__ __launch_bounds__(256) void gat_node(
    const float* __restrict__ xl, const float* __restrict__ xr,
    const float* __restrict__ att, const float* __restrict__ bias,
    const int* __restrict__ offsets, const int* __restrict__ csr_src,
    float* __restrict__ out, int n, int mode)
{
    int wid = threadIdx.x >> 6;
    int node = (blockIdx.x << 2) + wid;
    if (node >= n) return;
    int lane = threadIdx.x & 63;
    int l = lane & 15;
    int cb = ((lane >> 4) << 6) + (l << 2);   // channel base in [0,256)

    float4 xrv = *(const float4*)(xr + (size_t)node * HIDHC + cb);
    float4 atv = *(const float4*)(att + cb);
    float4 acc = make_float4(0.f, 0.f, 0.f, 0.f);
    float m = -INFINITY;
    float denom = 0.f;

    int j0 = offsets[node], j1 = offsets[node + 1];
    for (int j = j0; j < j1; ++j) {
        int s = csr_src[j];
        float4 v = *(const float4*)(xl + (size_t)s * HIDHC + cb);
        float e = lrelu(v.x + xrv.x) * atv.x
                + lrelu(v.y + xrv.y) * atv.y
                + lrelu(v.z + xrv.z) * atv.z
                + lrelu(v.w + xrv.w) * atv.w;
        e += __shfl_xor(e, 1);
        e += __shfl_xor(e, 2);
        e += __shfl_xor(e, 4);
        e += __shfl_xor(e, 8);
        float nm = fmaxf(m, e);
        float scale = __expf(m - nm);   // first edge: exp(-inf)=0
        float p = __expf(e - nm);
        denom = denom * scale + p;
        acc.x = fmaf(p, v.x, acc.x * scale);
        acc.y = fmaf(p, v.y, acc.y * scale);
        acc.z = fmaf(p, v.z, acc.z * scale);
        acc.w = fmaf(p, v.w, acc.w * scale);
        m = nm;
    }

    float inv = 1.f / (denom + 1e-16f);
    float4 o = make_float4(acc.x * inv, acc.y * inv, acc.z * inv, acc.w * inv);

    if (mode == 0) {
        // concat + bias1 + relu -> [N,256]
        float4 bv = *(const float4*)(bias + cb);
        o.x = fmaxf(o.x + bv.x, 0.f);
        o.y = fmaxf(o.y + bv.y, 0.f);
        o.z = fmaxf(o.z + bv.z, 0.f);
        o.w = fmaxf(o.w + bv.w, 0.f);
        *(float4*)(out + (size_t)node * HIDHC + cb) = o;
    } else {
        // mean over heads + bias2 + relu -> [N,64]
        o.x += __shfl_xor(o.x, 16); o.x += __shfl_xor(o.x, 32);
        o.y += __shfl_xor(o.y, 16); o.y += __shfl_xor(o.y, 32);
        o.z += __shfl_xor(o.z, 16); o.z += __shfl_xor(o.z, 32);
        o.w += __shfl_xor(o.w, 16); o.w += __shfl_xor(o.w, 32);
        float4 bv = *(const float4*)(bias + (l << 2));
        o.x = fmaxf(o.x * 0.25f + bv.x, 0.f);
        o.y = fmaxf(o.y * 0.25f + bv.y, 0.f);
        o.z = fmaxf(o.z * 0.25f + bv.z, 0.f);
        o.w = fmaxf(o.w * 0.25f + bv.w, 0.f);
        if ((lane >> 4) == 0)
            *(float4*)(out + (size_t)node * HID + (l << 2)) = o;
    }
}

// -------------------- final linear: out[N,40] = h2[N,64] @ Wc[64,40] + bc --------------------

__global__ __launch_bounds__(256) void final_linear(
    const float* __restrict__ h2, const float* __restrict__ Wc,
    const float* __restrict__ bc, float* __restrict__ out, int n)
{
    __shared__ float Ws[HID * OUT_DIM];
    __shared__ float bs[OUT_DIM];
    __shared__ float hs[64][HID + 1];

    for (int i = threadIdx.x; i < HID * OUT_DIM; i += 256) Ws[i] = Wc[i];
    if (threadIdx.x < OUT_DIM) bs[threadIdx.x] = bc[threadIdx.x];

    int n0 = blockIdx.x * 64;
    for (int i = threadIdx.x; i < 64 * HID; i += 256) {
        int r = i >> 6, c = i & 63;
        int node = n0 + r;
        hs[r][c] = (node < n) ? h2[(size_t)node * HID + c] : 0.f;
    }
    __syncthreads();

    for (int idx = threadIdx.x; idx < 64 * OUT_DIM; idx += 256) {
        int r = idx / OUT_DIM, o = idx % OUT_DIM;
        int node = n0 + r;
        if (node < n) {
            float s = bs[o];
            #pragma unroll
            for (int c = 0; c < HID; ++c) s = fmaf(hs[r][c], Ws[c * OUT_DIM + o], s);
            out[(size_t)node * OUT_DIM + o] = s;
        }
    }
}

// -------------------- launch --------------------

extern "C" void kernel_launch(void* const* d_in, const int* in_sizes, int n_in,
                              void* d_out, int out_size, void* d_ws, size_t ws_size,
                              hipStream_t stream) {
    const int N = in_sizes[0] / IN_DIM;   // 50000
    const int E = in_sizes[1];            // 800000

    const float* x    = (const float*)d_in[0];
    const int*   src  = (const int*)d_in[1];
    const int*   dst  = (const int*)d_in[2];
    const float* Wl1  = (const float*)d_in[3];
    const float* bl1  = (const float*)d_in[4];
    const float* Wr1  = (const float*)d_in[5];
    const float* br1  = (const float*)d_in[6];
    const float* att1 = (const float*)d_in[7];
    const float* bias1= (const float*)d_in[8];
    const float* Wl2  = (const float*)d_in[9];
    const float* bl2  = (const float*)d_in[10];
    const float* Wr2  = (const float*)d_in[11];
    const float* br2  = (const float*)d_in[12];
    const float* att2 = (const float*)d_in[13];
    const float* bias2= (const float*)d_in[14];
    const float* Wc   = (const float*)d_in[15];
    const float* bc   = (const float*)d_in[16];

    char* ws = (char*)d_ws;
    size_t off = 0;
    float* xl = (float*)(ws + off); off += (size_t)N * HIDHC * 4;
    float* xr = (float*)(ws + off); off += (size_t)N * HIDHC * 4;
    float* h1 = (float*)(ws + off); off += (size_t)N * HIDHC * 4;
    float* h2 = (float*)(ws + off); off += (size_t)N * HID * 4;
    int* deg     = (int*)(ws + off); off += (size_t)N * 4;
    int* offsets = (int*)(ws + off); off += (size_t)(N + 1) * 4;
    int* cursor  = (int*)(ws + off); off += (size_t)N * 4;
    int* csr     = (int*)(ws + off); off += (size_t)E * 4;

    // CSR build
    hipMemsetAsync(deg, 0, (size_t)N * 4, stream);
    edge_hist<<<(E + 255) / 256, 256, 0, stream>>>(dst, deg, E);
    scan_offsets<<<1, 1024, 0, stream>>>(deg, offsets, cursor, N);
    edge_scatter<<<(E + 255) / 256, 256, 0, stream>>>(src, dst, cursor, csr, E);

    dim3 gg((N + 127) / 128, 2);
    // layer 1
    gemm_f32<<<gg, 256, 0, stream>>>(x, Wl1, bl1, xl, N);
    gemm_f32<<<gg, 256, 0, stream>>>(x, Wr1, br1, xr, N);
    gat_node<<<(N + 3) / 4, 256, 0, stream>>>(xl, xr, att1, bias1, offsets, csr, h1, N, 0);
    // layer 2
    gemm_f32<<<gg, 256, 0, stream>>>(h1, Wl2, bl2, xl, N);
    gemm_f32<<<gg, 256, 0, stream>>>(h1, Wr2, br2, xr, N);
    gat_node<<<(N + 3) / 4, 256, 0, stream>>>(xl, xr, att2, bias2, offsets, csr, h2, N, 1);
    // head
    final_linear<<<(N + 63) / 64, 256, 0, stream>>>(h2, Wc, bc, (float*)d_out, N);
}